// Round 5
// baseline (106.077 us; speedup 1.0000x reference)
//
#include <hip/hip_runtime.h>
#include <math.h>

// ---------------- output offsets (floats) ----------------
#define O_Q     0
#define O_LOSS  2097152
#define O_IDX   2097153
#define O_PERP  2129921
#define O_NECS  2129922
#define O_EMAW  2130946
#define O_W     2196482

// ---------------- workspace offsets (4-byte units) ----------------
#define W_WT     0          // 65536  transposed weight [64][1024] fp32
#define W_SW2    65536      // 1024   (float, rounded from fp64)
#define W_CNT    99328      // 1024   counts
#define W_DW     100352     // 65536  dw
#define W_LOSS   165888     // 1      loss accum
#define W_CS     165952     // 1024   cluster_size
#define W_ZN     66561      // floats to zero starting at W_CNT (cnt+dw+loss)

// =====================================================================
// kernel 0: transpose weight -> wT[64][1024]; wsq[c] = fl32(fp64 sum w^2);
// also zero counts/dw/loss region (replaces hipMemsetAsync dispatch).
// =====================================================================
__global__ __launch_bounds__(256)
void k_prep(const float* __restrict__ w, float* __restrict__ wT,
            float* __restrict__ wsq, float* __restrict__ zbase) {
    __shared__ float sh[64][65];
    int tid = threadIdx.x;
    int j0 = blockIdx.x * 64;
    // zero stats region (grid-stride)
    for (int z = blockIdx.x * 256 + tid; z < W_ZN; z += 16 * 256) zbase[z] = 0.f;

    for (int p = 0; p < 16; ++p) {
        int f = p * 256 + tid;
        int j = f >> 6, d = f & 63;
        sh[j][d] = w[(j0 + j) * 64 + d];
    }
    __syncthreads();
    for (int p = 0; p < 16; ++p) {
        int f = p * 256 + tid;
        int d = f >> 6, jj = f & 63;
        wT[d * 1024 + j0 + jj] = sh[jj][d];
    }
    if (tid < 64) {
        double s = 0.0;
        #pragma unroll
        for (int d = 0; d < 64; ++d) {
            double v = (double)sh[tid][d];
            s = fma(v, v, s);
        }
        wsq[j0 + tid] = (float)s;
    }
}

// =====================================================================
// kernel 1 (fused): fp32 scores + argmin + quantized out + loss + counts + dw.
// np-emulating score: fl32( fl32(rsq[r]+wsq[c]) - 2*dot_f32 ).
// tile: 128 rows x 256-code chunks (4 chunks = all codes -> index final
// in-block, enabling fusion); 512 thr as 16ty x 32tx, 8x8 micro-tile.
// Inner k-loop is software-pipelined 2-deep: load batch k+1 while FMA'ing k.
// =====================================================================
#define LOADK(K, A0, A1, B0, B1)                         \
    { A0 = *(const float4*)&xs[K][ty4];                  \
      A1 = *(const float4*)&xs[K][64 + ty4];             \
      B0 = *(const float4*)&wsh[K][tx4];                 \
      B1 = *(const float4*)&wsh[K][128 + tx4]; }

#define FMAB(A0, A1, B0, B1)                                              \
    { float xr[2][4] = {{A0.x, A0.y, A0.z, A0.w}, {A1.x, A1.y, A1.z, A1.w}}; \
      float wc[2][4] = {{B0.x, B0.y, B0.z, B0.w}, {B1.x, B1.y, B1.z, B1.w}}; \
      _Pragma("unroll")                                                   \
      for (int rp = 0; rp < 2; ++rp)                                      \
        _Pragma("unroll")                                                 \
        for (int cp = 0; cp < 2; ++cp)                                    \
          _Pragma("unroll")                                               \
          for (int i = 0; i < 4; ++i)                                     \
            _Pragma("unroll")                                             \
            for (int j = 0; j < 4; ++j)                                   \
              acc[rp][cp][i][j] += xr[rp][i] * wc[cp][j]; }

__global__ __launch_bounds__(512, 2)
void k_dist(const float* __restrict__ x, const float* __restrict__ wT,
            const float* __restrict__ wsq, const float* __restrict__ w,
            float* __restrict__ out_idxf, float* __restrict__ outq,
            float* __restrict__ counts, float* __restrict__ dw,
            float* __restrict__ loss) {
    __shared__ float xs[64][132];    // [k][row], padded (odd-ish stride for dw phase)
    __shared__ float wsh[64][256];   // [k][code] per chunk
    __shared__ float rsq[128];
    __shared__ float wsqs[256];
    __shared__ int   idxl[128];
    __shared__ float red[8];
    int tid = threadIdx.x;
    int tx = tid & 31, ty = tid >> 5;
    int tx4 = tx * 4, ty4 = ty * 4;
    int rbase = blockIdx.x * 128;
    int b = rbase >> 10, hw0 = rbase & 1023;
    const float* xb = x + b * 65536 + hw0;

    // stage x tile: xs[d][r]
    for (int p = 0; p < 4; ++p) {
        int f = p * 512 + tid;
        int d = f >> 5, r4 = (f & 31) << 2;
        *(float4*)&xs[d][r4] = *(const float4*)(xb + d * 1024 + r4);
    }
    __syncthreads();
    if (tid < 128) {
        double s = 0.0;
        #pragma unroll
        for (int d = 0; d < 64; ++d) {
            double v = (double)xs[d][tid];
            s = fma(v, v, s);
        }
        rsq[tid] = (float)s;
    }

    float best[2][4];
    int   bidx[2][4];
    #pragma unroll
    for (int rp = 0; rp < 2; ++rp)
        #pragma unroll
        for (int i = 0; i < 4; ++i) { best[rp][i] = 3.4e38f; bidx[rp][i] = 0; }

    for (int ch = 0; ch < 4; ++ch) {
        int cb = ch * 256;
        __syncthreads();   // protect wsh reuse; orders rsq/xs on ch==0
        for (int p = 0; p < 8; ++p) {
            int f = p * 512 + tid;
            int k = f >> 6, c4 = (f & 63) << 2;
            *(float4*)&wsh[k][c4] = *(const float4*)(wT + k * 1024 + cb + c4);
        }
        if (tid < 64) *(float4*)&wsqs[tid * 4] = *(const float4*)(wsq + cb + tid * 4);
        __syncthreads();

        float acc[2][2][4][4];
        #pragma unroll
        for (int rp = 0; rp < 2; ++rp)
            #pragma unroll
            for (int cp = 0; cp < 2; ++cp)
                #pragma unroll
                for (int i = 0; i < 4; ++i)
                    #pragma unroll
                    for (int j = 0; j < 4; ++j) acc[rp][cp][i][j] = 0.f;

        // 2-deep software-pipelined k loop
        float4 a0, a1, b0, b1, c0, c1, d0, d1;
        LOADK(0, a0, a1, b0, b1);
        for (int k = 0; k < 64; k += 2) {
            LOADK(k + 1, c0, c1, d0, d1);
            FMAB(a0, a1, b0, b1);
            int kn = (k + 2 < 64) ? (k + 2) : 62;   // last preload unused
            LOADK(kn, a0, a1, b0, b1);
            FMAB(c0, c1, d0, d1);
        }

        // score; c ascending within thread => strict < keeps first min
        #pragma unroll
        for (int cp = 0; cp < 2; ++cp)
            #pragma unroll
            for (int j = 0; j < 4; ++j) {
                int cl = cp * 128 + tx4 + j;
                float s2 = wsqs[cl];
                int c = cb + cl;
                #pragma unroll
                for (int rp = 0; rp < 2; ++rp)
                    #pragma unroll
                    for (int i = 0; i < 4; ++i) {
                        float t1 = rsq[rp * 64 + ty4 + i] + s2;   // fl32 add @ ~64
                        float sc = t1 - 2.0f * acc[rp][cp][i][j]; // one rounding
                        if (sc < best[rp][i]) { best[rp][i] = sc; bidx[rp][i] = c; }
                    }
            }
    }

    // argmin reduce across 32 tx-lanes (tie -> lower index)
    #pragma unroll
    for (int off = 1; off < 32; off <<= 1) {
        #pragma unroll
        for (int rp = 0; rp < 2; ++rp)
            #pragma unroll
            for (int i = 0; i < 4; ++i) {
                float ov = __shfl_xor(best[rp][i], off);
                int   oi = __shfl_xor(bidx[rp][i], off);
                if (ov < best[rp][i] ||
                    (ov == best[rp][i] && oi < bidx[rp][i])) {
                    best[rp][i] = ov; bidx[rp][i] = oi;
                }
            }
    }
    if (tx == 0) {
        #pragma unroll
        for (int rp = 0; rp < 2; ++rp)
            #pragma unroll
            for (int i = 0; i < 4; ++i) {
                int rl = rp * 64 + ty4 + i;
                idxl[rl] = bidx[rp][i];
                out_idxf[rbase + rl] = (float)bidx[rp][i];
            }
    }
    __syncthreads();

    // ---- fused quant phase (xs still resident) ----
    if (tid < 128) atomicAdd(&counts[idxl[tid]], 1.0f);

    float ll = 0.f;
    for (int p = 0; p < 16; ++p) {
        int f = p * 512 + tid;
        int d = f >> 7, n = f & 127;
        float q  = w[idxl[n] * 64 + d];     // L2-resident gather
        float xv = xs[d][n];
        float dd = q - xv;
        ll += dd * dd;
        outq[b * 65536 + d * 1024 + hw0 + n] = q;   // coalesced
    }
    #pragma unroll
    for (int off = 32; off; off >>= 1) ll += __shfl_down(ll, off);
    if ((tid & 63) == 0) red[tid >> 6] = ll;
    __syncthreads();
    if (tid == 0) {
        float s = 0.f;
        #pragma unroll
        for (int i = 0; i < 8; ++i) s += red[i];
        atomicAdd(loss, s);
    }

    // dw: lane = d, one coalesced 256B atomic row per vector
    int wv = tid >> 6, lane = tid & 63;
    for (int v = 0; v < 16; ++v) {
        int n = wv * 16 + v;
        atomicAdd(&dw[idxl[n] * 64 + lane], xs[lane][n]);
    }
}

// =====================================================================
// kernel 2a: scalars + cluster_size (single block, 1024 threads)
// =====================================================================
__global__ __launch_bounds__(1024)
void k_final_a(const float* __restrict__ ema_cs, const float* __restrict__ counts,
               const float* __restrict__ loss, float* __restrict__ cs_ws,
               float* __restrict__ out) {
    __shared__ float redA[16], redB[16];
    __shared__ float ntot_sh;
    int tid = threadIdx.x;

    float c    = counts[tid];
    float necs = 0.99f * ema_cs[tid] + 0.01f * c;
    out[O_NECS + tid] = necs;

    float p   = c * (1.0f / 32768.0f);
    float ent = -p * logf(p + 1e-10f);

    float s1 = necs, s2 = ent;
    #pragma unroll
    for (int off = 32; off; off >>= 1) {
        s1 += __shfl_down(s1, off);
        s2 += __shfl_down(s2, off);
    }
    int wv = tid >> 6;
    if ((tid & 63) == 0) { redA[wv] = s1; redB[wv] = s2; }
    __syncthreads();
    if (tid == 0) {
        float t1 = 0.f, t2 = 0.f;
        for (int i = 0; i < 16; ++i) { t1 += redA[i]; t2 += redB[i]; }
        ntot_sh = t1;
        out[O_PERP] = expf(t2);
        out[O_LOSS] = 0.25f * loss[0] * (1.0f / 2097152.0f);
    }
    __syncthreads();
    float ntot = ntot_sh;
    cs_ws[tid] = (necs + 1e-5f) / (ntot + 1024.0f * 1e-5f) * ntot;
}

// =====================================================================
// kernel 2b: EMA-w + new weight (256 blocks x 256 threads)
// =====================================================================
__global__ __launch_bounds__(256)
void k_final_b(const float* __restrict__ ema_w, const float* __restrict__ dw,
               const float* __restrict__ cs_ws, float* __restrict__ out) {
    int f = blockIdx.x * 256 + threadIdx.x;
    int j = f >> 6;
    float ne = 0.99f * ema_w[f] + 0.01f * dw[f];
    out[O_EMAW + f] = ne;
    out[O_W + f]    = ne / cs_ws[j];
}

// =====================================================================
extern "C" void kernel_launch(void* const* d_in, const int* in_sizes, int n_in,
                              void* d_out, int out_size, void* d_ws, size_t ws_size,
                              hipStream_t stream) {
    const float* x      = (const float*)d_in[0];
    const float* w      = (const float*)d_in[1];
    const float* ema_cs = (const float*)d_in[2];
    const float* ema_w  = (const float*)d_in[3];
    float* out = (float*)d_out;
    float* ws  = (float*)d_ws;

    float* wT     = ws + W_WT;
    float* wsq    = ws + W_SW2;
    float* counts = ws + W_CNT;
    float* dwb    = ws + W_DW;
    float* lossb  = ws + W_LOSS;
    float* cs_ws  = ws + W_CS;

    k_prep   <<<16,  256, 0, stream>>>(w, wT, wsq, counts);
    k_dist   <<<256, 512, 0, stream>>>(x, wT, wsq, w, out + O_IDX, out + O_Q,
                                       counts, dwb, lossb);
    k_final_a<<<1,  1024, 0, stream>>>(ema_cs, counts, lossb, cs_ws, out);
    k_final_b<<<256, 256, 0, stream>>>(ema_w, dwb, cs_ws, out);
}

// Round 6
// 100.162 us; speedup vs baseline: 1.0591x; 1.0591x over previous
//
#include <hip/hip_runtime.h>
#include <math.h>

// ---------------- output offsets (floats) ----------------
#define O_Q     0
#define O_LOSS  2097152
#define O_IDX   2097153
#define O_PERP  2129921
#define O_NECS  2129922
#define O_EMAW  2130946
#define O_W     2196482

// ---------------- workspace offsets (4-byte units) ----------------
#define W_WT     0          // 65536  transposed weight [64][1024] fp32
#define W_SW2    65536      // 1024   (float, rounded from fp64)
#define W_IDX    66560      // 32768  (int)
#define W_CNT    99328      // 1024   counts
#define W_DW     100352     // 65536  dw
#define W_LOSS   165888     // 1      loss accum
#define W_CS     165952     // 1024   cluster_size
#define W_ZN     66561      // floats to zero starting at W_CNT (cnt+dw+loss)

// =====================================================================
// kernel 0: transpose weight -> wT[64][1024]; wsq[c] = fl32(fp64 sum w^2);
// also zero counts/dw/loss region (replaces hipMemsetAsync dispatch).
// =====================================================================
__global__ __launch_bounds__(256)
void k_prep(const float* __restrict__ w, float* __restrict__ wT,
            float* __restrict__ wsq, float* __restrict__ zbase) {
    __shared__ float sh[64][65];
    int tid = threadIdx.x;
    int j0 = blockIdx.x * 64;
    for (int z = blockIdx.x * 256 + tid; z < W_ZN; z += 16 * 256) zbase[z] = 0.f;

    for (int p = 0; p < 16; ++p) {
        int f = p * 256 + tid;
        int j = f >> 6, d = f & 63;
        sh[j][d] = w[(j0 + j) * 64 + d];
    }
    __syncthreads();
    for (int p = 0; p < 16; ++p) {
        int f = p * 256 + tid;
        int d = f >> 6, jj = f & 63;
        wT[d * 1024 + j0 + jj] = sh[jj][d];
    }
    if (tid < 64) {
        double s = 0.0;
        #pragma unroll
        for (int d = 0; d < 64; ++d) {
            double v = (double)sh[tid][d];
            s = fma(v, v, s);
        }
        wsq[j0 + tid] = (float)s;
    }
}

// =====================================================================
// kernel 1: fp32 scores + argmin (np-emulating expression tree, bitwise
// identical accumulation order to the round-4 PASSING kernel):
//   score = fl32( fl32(rsq[r] + wsq[c]) - 2*dot_f32 ), dot = seq fp32 FMA k=0..63
// NEW geometry for occupancy: tile 64 rows x 1024 codes; staged as
// 2 code-chunks (512 wide) x 2 k-halves (32 deep). LDS ~75.5 KB ->
// 2 blocks/CU, 16 waves/CU (was 8). grid 512, block 512 (8ty x 64tx),
// microtile 8 rows x 8 codes. x-frag reads are wave-uniform broadcasts;
// w-frag reads are 1024B-contiguous per wave (conflict-free).
// =====================================================================
__global__ __launch_bounds__(512, 2)
void k_dist(const float* __restrict__ x, const float* __restrict__ wT,
            const float* __restrict__ wsq,
            int* __restrict__ idx_int, float* __restrict__ out_idxf) {
    __shared__ float xs[32][64];     // [k-half][row]   8 KB
    __shared__ float wsh[32][512];   // [k-half][code] 64 KB
    __shared__ float rsq[64];
    __shared__ float wsqs[512];
    int tid = threadIdx.x;
    int tx = tid & 63, ty = tid >> 6;
    int rbase = blockIdx.x * 64;
    int b = rbase >> 10, hw0 = rbase & 1023;
    const float* xb = x + b * 65536 + hw0;

    int sd = tid >> 4, sr4 = (tid & 15) << 2;   // xs staging coords

    float best[8];
    int   bidx[8];
    #pragma unroll
    for (int i = 0; i < 8; ++i) { best[i] = 3.4e38f; bidx[i] = 0; }
    double rsq_acc = 0.0;

    for (int ch = 0; ch < 2; ++ch) {
        int cb = ch * 512;
        float acc[2][2][4][4];
        #pragma unroll
        for (int rp = 0; rp < 2; ++rp)
            #pragma unroll
            for (int cp = 0; cp < 2; ++cp)
                #pragma unroll
                for (int i = 0; i < 4; ++i)
                    #pragma unroll
                    for (int j = 0; j < 4; ++j) acc[rp][cp][i][j] = 0.f;

        for (int h = 0; h < 2; ++h) {
            int k0 = h * 32;
            __syncthreads();   // protect xs/wsh/wsqs reuse
            *(float4*)&xs[sd][sr4] = *(const float4*)(xb + (k0 + sd) * 1024 + sr4);
            #pragma unroll
            for (int p = 0; p < 8; ++p) {
                int f = p * 512 + tid;
                int kk = f >> 7, c4 = (f & 127) << 2;
                *(float4*)&wsh[kk][c4] = *(const float4*)(wT + (k0 + kk) * 1024 + cb + c4);
            }
            if (h == 0 && tid < 128)
                *(float4*)&wsqs[tid * 4] = *(const float4*)(wsq + cb + tid * 4);
            __syncthreads();

            if (ch == 0 && tid < 64) {      // fp64 row norms, k ascending
                #pragma unroll
                for (int kk = 0; kk < 32; ++kk) {
                    double v = (double)xs[kk][tid];
                    rsq_acc = fma(v, v, rsq_acc);
                }
            }

            #pragma unroll 4
            for (int kk = 0; kk < 32; ++kk) {
                float4 xa0 = *(float4*)&xs[kk][ty * 8];
                float4 xa1 = *(float4*)&xs[kk][ty * 8 + 4];
                float4 wb0 = *(float4*)&wsh[kk][tx * 4];
                float4 wb1 = *(float4*)&wsh[kk][256 + tx * 4];
                float xr[2][4] = {{xa0.x, xa0.y, xa0.z, xa0.w},
                                  {xa1.x, xa1.y, xa1.z, xa1.w}};
                float wc[2][4] = {{wb0.x, wb0.y, wb0.z, wb0.w},
                                  {wb1.x, wb1.y, wb1.z, wb1.w}};
                #pragma unroll
                for (int rp = 0; rp < 2; ++rp)
                    #pragma unroll
                    for (int cp = 0; cp < 2; ++cp)
                        #pragma unroll
                        for (int i = 0; i < 4; ++i)
                            #pragma unroll
                            for (int j = 0; j < 4; ++j)
                                acc[rp][cp][i][j] += xr[rp][i] * wc[cp][j];
            }
        }

        if (ch == 0) {
            if (tid < 64) rsq[tid] = (float)rsq_acc;
            __syncthreads();
        }

        // scoring; (ch, cp, j) ascending => strict < keeps first min
        float4 wsa = *(float4*)&wsqs[tx * 4];
        float4 wsb = *(float4*)&wsqs[256 + tx * 4];
        float s2v[2][4] = {{wsa.x, wsa.y, wsa.z, wsa.w},
                           {wsb.x, wsb.y, wsb.z, wsb.w}};
        #pragma unroll
        for (int cp = 0; cp < 2; ++cp)
            #pragma unroll
            for (int j = 0; j < 4; ++j) {
                int c = cb + cp * 256 + tx * 4 + j;
                float s2 = s2v[cp][j];
                #pragma unroll
                for (int rp = 0; rp < 2; ++rp)
                    #pragma unroll
                    for (int i = 0; i < 4; ++i) {
                        int rl = rp * 4 + i;
                        float t1 = rsq[ty * 8 + rl] + s2;          // fl32 add @ ~64
                        float sc = t1 - 2.0f * acc[rp][cp][i][j];  // one rounding
                        if (sc < best[rl]) { best[rl] = sc; bidx[rl] = c; }
                    }
            }
    }

    // argmin reduce across all 64 lanes (ty is wave-uniform; lanes = tx)
    #pragma unroll
    for (int off = 1; off < 64; off <<= 1) {
        #pragma unroll
        for (int i = 0; i < 8; ++i) {
            float ov = __shfl_xor(best[i], off);
            int   oi = __shfl_xor(bidx[i], off);
            if (ov < best[i] || (ov == best[i] && oi < bidx[i])) {
                best[i] = ov; bidx[i] = oi;
            }
        }
    }
    if (tx == 0) {
        #pragma unroll
        for (int i = 0; i < 8; ++i) {
            int r = rbase + ty * 8 + i;
            idx_int[r]  = bidx[i];
            out_idxf[r] = (float)bidx[i];
        }
    }
}

// =====================================================================
// kernel 2: quantized output + loss + counts + dw (block = 64 vectors)
// xs stride 65 -> dw column reads are 2-way (free); round-4-verified.
// =====================================================================
__global__ __launch_bounds__(256)
void k_quant(const float* __restrict__ x, const float* __restrict__ w,
             const int* __restrict__ idx_int, float* __restrict__ outq,
             float* __restrict__ counts, float* __restrict__ dw,
             float* __restrict__ loss) {
    __shared__ float xs[64][65];
    __shared__ int   idxl[64];
    __shared__ float red[4];
    int tid = threadIdx.x;
    int n0  = blockIdx.x * 64;
    int b   = n0 >> 10, hw0 = n0 & 1023;
    const float* xb = x + b * 65536 + hw0;

    if (tid < 64) {
        int id = idx_int[n0 + tid];
        idxl[tid] = id;
        atomicAdd(&counts[id], 1.0f);
    }
    for (int p = 0; p < 16; ++p) {
        int f = p * 256 + tid;
        int d = f >> 6, n = f & 63;
        xs[d][n] = xb[d * 1024 + n];
    }
    __syncthreads();

    float ll = 0.f;
    for (int p = 0; p < 16; ++p) {
        int f = p * 256 + tid;
        int d = f >> 6, n = f & 63;
        float q  = w[idxl[n] * 64 + d];
        float xv = xs[d][n];
        float dd = q - xv;
        ll += dd * dd;
        outq[b * 65536 + d * 1024 + hw0 + n] = q;
    }
    #pragma unroll
    for (int off = 32; off; off >>= 1) ll += __shfl_down(ll, off);
    if ((tid & 63) == 0) red[tid >> 6] = ll;
    __syncthreads();
    if (tid == 0) atomicAdd(loss, red[0] + red[1] + red[2] + red[3]);

    // dw: lane = d, one coalesced 256B atomic row per vector
    int wv = tid >> 6, lane = tid & 63;
    for (int v = 0; v < 16; ++v) {
        int n = wv * 16 + v;
        atomicAdd(&dw[idxl[n] * 64 + lane], xs[lane][n]);
    }
}

// =====================================================================
// kernel 3a: scalars + cluster_size (single block, 1024 threads)
// =====================================================================
__global__ __launch_bounds__(1024)
void k_final_a(const float* __restrict__ ema_cs, const float* __restrict__ counts,
               const float* __restrict__ loss, float* __restrict__ cs_ws,
               float* __restrict__ out) {
    __shared__ float redA[16], redB[16];
    __shared__ float ntot_sh;
    int tid = threadIdx.x;

    float c    = counts[tid];
    float necs = 0.99f * ema_cs[tid] + 0.01f * c;
    out[O_NECS + tid] = necs;

    float p   = c * (1.0f / 32768.0f);
    float ent = -p * logf(p + 1e-10f);

    float s1 = necs, s2 = ent;
    #pragma unroll
    for (int off = 32; off; off >>= 1) {
        s1 += __shfl_down(s1, off);
        s2 += __shfl_down(s2, off);
    }
    int wv = tid >> 6;
    if ((tid & 63) == 0) { redA[wv] = s1; redB[wv] = s2; }
    __syncthreads();
    if (tid == 0) {
        float t1 = 0.f, t2 = 0.f;
        for (int i = 0; i < 16; ++i) { t1 += redA[i]; t2 += redB[i]; }
        ntot_sh = t1;
        out[O_PERP] = expf(t2);
        out[O_LOSS] = 0.25f * loss[0] * (1.0f / 2097152.0f);
    }
    __syncthreads();
    float ntot = ntot_sh;
    cs_ws[tid] = (necs + 1e-5f) / (ntot + 1024.0f * 1e-5f) * ntot;
}

// =====================================================================
// kernel 3b: EMA-w + new weight (256 blocks x 256 threads)
// =====================================================================
__global__ __launch_bounds__(256)
void k_final_b(const float* __restrict__ ema_w, const float* __restrict__ dw,
               const float* __restrict__ cs_ws, float* __restrict__ out) {
    int f = blockIdx.x * 256 + threadIdx.x;
    int j = f >> 6;
    float ne = 0.99f * ema_w[f] + 0.01f * dw[f];
    out[O_EMAW + f] = ne;
    out[O_W + f]    = ne / cs_ws[j];
}

// =====================================================================
extern "C" void kernel_launch(void* const* d_in, const int* in_sizes, int n_in,
                              void* d_out, int out_size, void* d_ws, size_t ws_size,
                              hipStream_t stream) {
    const float* x      = (const float*)d_in[0];
    const float* w      = (const float*)d_in[1];
    const float* ema_cs = (const float*)d_in[2];
    const float* ema_w  = (const float*)d_in[3];
    float* out = (float*)d_out;
    float* ws  = (float*)d_ws;

    float* wT     = ws + W_WT;
    float* wsq    = ws + W_SW2;
    int*   idxi   = (int*)(ws + W_IDX);
    float* counts = ws + W_CNT;
    float* dwb    = ws + W_DW;
    float* lossb  = ws + W_LOSS;
    float* cs_ws  = ws + W_CS;

    k_prep   <<<16,  256, 0, stream>>>(w, wT, wsq, counts);
    k_dist   <<<512, 512, 0, stream>>>(x, wT, wsq, idxi, out + O_IDX);
    k_quant  <<<512, 256, 0, stream>>>(x, w, idxi, out + O_Q, counts, dwb, lossb);
    k_final_a<<<1,  1024, 0, stream>>>(ema_cs, counts, lossb, cs_ws, out);
    k_final_b<<<256, 256, 0, stream>>>(ema_w, dwb, cs_ws, out);
}

// Round 7
// 94.510 us; speedup vs baseline: 1.1224x; 1.0598x over previous
//
#include <hip/hip_runtime.h>
#include <math.h>

// ---------------- output offsets (floats) ----------------
#define O_Q     0
#define O_LOSS  2097152
#define O_IDX   2097153
#define O_PERP  2129921
#define O_NECS  2129922
#define O_EMAW  2130946
#define O_W     2196482

// ---------------- workspace offsets (4-byte units) ----------------
#define W_WT     0          // 65536  transposed weight [64][1024] fp32
#define W_SW2    65536      // 1024   (float, rounded from fp64)
#define W_IDX    66560      // 32768  (int)
#define W_CNT    99328      // 1024   counts
#define W_DW     100352     // 65536  dw
#define W_LOSS   165888     // 1      loss accum
#define W_CS     165952     // 1024   cluster_size
#define W_ZN     66561      // floats to zero starting at W_CNT (cnt+dw+loss)

// =====================================================================
// kernel 0: transpose weight -> wT[64][1024]; wsq[c] = fl32(fp64 sum w^2);
// also zero counts/dw/loss region (replaces hipMemsetAsync dispatch).
// =====================================================================
__global__ __launch_bounds__(256)
void k_prep(const float* __restrict__ w, float* __restrict__ wT,
            float* __restrict__ wsq, float* __restrict__ zbase) {
    __shared__ float sh[64][65];
    int tid = threadIdx.x;
    int j0 = blockIdx.x * 64;
    for (int z = blockIdx.x * 256 + tid; z < W_ZN; z += 16 * 256) zbase[z] = 0.f;

    for (int p = 0; p < 16; ++p) {
        int f = p * 256 + tid;
        int j = f >> 6, d = f & 63;
        sh[j][d] = w[(j0 + j) * 64 + d];
    }
    __syncthreads();
    for (int p = 0; p < 16; ++p) {
        int f = p * 256 + tid;
        int d = f >> 6, jj = f & 63;
        wT[d * 1024 + j0 + jj] = sh[jj][d];
    }
    if (tid < 64) {
        double s = 0.0;
        #pragma unroll
        for (int d = 0; d < 64; ++d) {
            double v = (double)sh[tid][d];
            s = fma(v, v, s);
        }
        wsq[j0 + tid] = (float)s;
    }
}

// =====================================================================
// kernel 1: fp32 scores + argmin. Round-4 frame (128 rows x 256-code
// chunks x 4, 64 k-steps per staging barrier) with broadcast-x mapping:
// block 512 = 8 ty x 64 tx; microtile 16 rows x 4 codes per thread.
// Per k-step: 4 wave-uniform broadcast x-reads (~free) + 1 ds_read_b128
// w-read -> LDS pipe ~160 cyc/CU/k vs VALU 256 -> VALU-bound.
// Numerics bitwise-identical to the round-4 PASSING kernel:
//   score = fl32( fl32(rsq[r]+wsq[c]) - 2*dot ), dot = seq fp32 FMA k=0..63,
//   rsq/wsq = fl32(fp64 sums), ties -> lowest code index.
// =====================================================================
__global__ __launch_bounds__(512, 2)
void k_dist(const float* __restrict__ x, const float* __restrict__ wT,
            const float* __restrict__ wsq,
            int* __restrict__ idx_int, float* __restrict__ out_idxf) {
    __shared__ float xs[64][128];    // [k][row]   32 KB (resident all chunks)
    __shared__ float wsh[64][256];   // [k][code]  64 KB (per chunk)
    __shared__ float rsq[128];
    __shared__ float wsqs[256];
    int tid = threadIdx.x;
    int tx = tid & 63, ty = tid >> 6;     // tx: codes (full wave), ty: row group
    int r0 = ty * 16;                      // first of this thread's 16 rows
    int rbase = blockIdx.x * 128;
    int b = rbase >> 10, hw0 = rbase & 1023;
    const float* xb = x + b * 65536 + hw0;

    // stage x tile: xs[d][r] (once; resident for all 4 chunks)
    for (int p = 0; p < 4; ++p) {
        int f = p * 512 + tid;
        int d = f >> 5, r4 = (f & 31) << 2;
        *(float4*)&xs[d][r4] = *(const float4*)(xb + d * 1024 + r4);
    }
    __syncthreads();
    if (tid < 128) {                       // fp64 row norms, k ascending
        double s = 0.0;
        #pragma unroll
        for (int d = 0; d < 64; ++d) {
            double v = (double)xs[d][tid];
            s = fma(v, v, s);
        }
        rsq[tid] = (float)s;
    }

    float best[16];
    int   bidx[16];
    #pragma unroll
    for (int i = 0; i < 16; ++i) { best[i] = 3.4e38f; bidx[i] = 0; }

    for (int ch = 0; ch < 4; ++ch) {
        int cb = ch * 256;
        __syncthreads();   // protect wsh/wsqs reuse; orders rsq on ch==0
        for (int p = 0; p < 8; ++p) {
            int f = p * 512 + tid;
            int k = f >> 6, c4 = (f & 63) << 2;
            *(float4*)&wsh[k][c4] = *(const float4*)(wT + k * 1024 + cb + c4);
        }
        if (tid < 64) *(float4*)&wsqs[tid * 4] = *(const float4*)(wsq + cb + tid * 4);
        __syncthreads();

        float acc[16][4];
        #pragma unroll
        for (int i = 0; i < 16; ++i)
            #pragma unroll
            for (int j = 0; j < 4; ++j) acc[i][j] = 0.f;

        #pragma unroll 2
        for (int k = 0; k < 64; ++k) {
            // 4 wave-uniform broadcast reads (ty uniform across the wave)
            float4 xa0 = *(float4*)&xs[k][r0];
            float4 xa1 = *(float4*)&xs[k][r0 + 4];
            float4 xa2 = *(float4*)&xs[k][r0 + 8];
            float4 xa3 = *(float4*)&xs[k][r0 + 12];
            float4 wb  = *(float4*)&wsh[k][tx * 4];
            float xr[16] = {xa0.x, xa0.y, xa0.z, xa0.w,
                            xa1.x, xa1.y, xa1.z, xa1.w,
                            xa2.x, xa2.y, xa2.z, xa2.w,
                            xa3.x, xa3.y, xa3.z, xa3.w};
            float wc[4]  = {wb.x, wb.y, wb.z, wb.w};
            #pragma unroll
            for (int i = 0; i < 16; ++i)
                #pragma unroll
                for (int j = 0; j < 4; ++j)
                    acc[i][j] += xr[i] * wc[j];
        }

        // scoring; (ch, j) ascending per thread => strict < keeps first min
        float4 wsa = *(float4*)&wsqs[tx * 4];
        float s2v[4] = {wsa.x, wsa.y, wsa.z, wsa.w};
        #pragma unroll
        for (int j = 0; j < 4; ++j) {
            int c = cb + tx * 4 + j;
            float s2 = s2v[j];
            #pragma unroll
            for (int i = 0; i < 16; ++i) {
                float t1 = rsq[r0 + i] + s2;       // fl32 add @ ~64 (broadcast read)
                float sc = t1 - 2.0f * acc[i][j];  // 2*dot exact; one rounding
                if (sc < best[i]) { best[i] = sc; bidx[i] = c; }
            }
        }
    }

    // argmin reduce across all 64 lanes (codes live on lanes; tie -> lower idx)
    #pragma unroll
    for (int off = 1; off < 64; off <<= 1) {
        #pragma unroll
        for (int i = 0; i < 16; ++i) {
            float ov = __shfl_xor(best[i], off);
            int   oi = __shfl_xor(bidx[i], off);
            if (ov < best[i] || (ov == best[i] && oi < bidx[i])) {
                best[i] = ov; bidx[i] = oi;
            }
        }
    }
    if (tx == 0) {
        #pragma unroll
        for (int i = 0; i < 16; ++i) {
            int r = rbase + r0 + i;
            idx_int[r]  = bidx[i];
            out_idxf[r] = (float)bidx[i];
        }
    }
}

// =====================================================================
// kernel 2: quantized output + loss + counts + dw (block = 64 vectors)
// xs stride 65 -> dw column reads are 2-way (free); round-4-verified.
// =====================================================================
__global__ __launch_bounds__(256)
void k_quant(const float* __restrict__ x, const float* __restrict__ w,
             const int* __restrict__ idx_int, float* __restrict__ outq,
             float* __restrict__ counts, float* __restrict__ dw,
             float* __restrict__ loss) {
    __shared__ float xs[64][65];
    __shared__ int   idxl[64];
    __shared__ float red[4];
    int tid = threadIdx.x;
    int n0  = blockIdx.x * 64;
    int b   = n0 >> 10, hw0 = n0 & 1023;
    const float* xb = x + b * 65536 + hw0;

    if (tid < 64) {
        int id = idx_int[n0 + tid];
        idxl[tid] = id;
        atomicAdd(&counts[id], 1.0f);
    }
    for (int p = 0; p < 16; ++p) {
        int f = p * 256 + tid;
        int d = f >> 6, n = f & 63;
        xs[d][n] = xb[d * 1024 + n];
    }
    __syncthreads();

    float ll = 0.f;
    for (int p = 0; p < 16; ++p) {
        int f = p * 256 + tid;
        int d = f >> 6, n = f & 63;
        float q  = w[idxl[n] * 64 + d];
        float xv = xs[d][n];
        float dd = q - xv;
        ll += dd * dd;
        outq[b * 65536 + d * 1024 + hw0 + n] = q;
    }
    #pragma unroll
    for (int off = 32; off; off >>= 1) ll += __shfl_down(ll, off);
    if ((tid & 63) == 0) red[tid >> 6] = ll;
    __syncthreads();
    if (tid == 0) atomicAdd(loss, red[0] + red[1] + red[2] + red[3]);

    // dw: lane = d, one coalesced 256B atomic row per vector
    int wv = tid >> 6, lane = tid & 63;
    for (int v = 0; v < 16; ++v) {
        int n = wv * 16 + v;
        atomicAdd(&dw[idxl[n] * 64 + lane], xs[lane][n]);
    }
}

// =====================================================================
// kernel 3a: scalars + cluster_size (single block, 1024 threads)
// =====================================================================
__global__ __launch_bounds__(1024)
void k_final_a(const float* __restrict__ ema_cs, const float* __restrict__ counts,
               const float* __restrict__ loss, float* __restrict__ cs_ws,
               float* __restrict__ out) {
    __shared__ float redA[16], redB[16];
    __shared__ float ntot_sh;
    int tid = threadIdx.x;

    float c    = counts[tid];
    float necs = 0.99f * ema_cs[tid] + 0.01f * c;
    out[O_NECS + tid] = necs;

    float p   = c * (1.0f / 32768.0f);
    float ent = -p * logf(p + 1e-10f);

    float s1 = necs, s2 = ent;
    #pragma unroll
    for (int off = 32; off; off >>= 1) {
        s1 += __shfl_down(s1, off);
        s2 += __shfl_down(s2, off);
    }
    int wv = tid >> 6;
    if ((tid & 63) == 0) { redA[wv] = s1; redB[wv] = s2; }
    __syncthreads();
    if (tid == 0) {
        float t1 = 0.f, t2 = 0.f;
        for (int i = 0; i < 16; ++i) { t1 += redA[i]; t2 += redB[i]; }
        ntot_sh = t1;
        out[O_PERP] = expf(t2);
        out[O_LOSS] = 0.25f * loss[0] * (1.0f / 2097152.0f);
    }
    __syncthreads();
    float ntot = ntot_sh;
    cs_ws[tid] = (necs + 1e-5f) / (ntot + 1024.0f * 1e-5f) * ntot;
}

// =====================================================================
// kernel 3b: EMA-w + new weight (256 blocks x 256 threads)
// =====================================================================
__global__ __launch_bounds__(256)
void k_final_b(const float* __restrict__ ema_w, const float* __restrict__ dw,
               const float* __restrict__ cs_ws, float* __restrict__ out) {
    int f = blockIdx.x * 256 + threadIdx.x;
    int j = f >> 6;
    float ne = 0.99f * ema_w[f] + 0.01f * dw[f];
    out[O_EMAW + f] = ne;
    out[O_W + f]    = ne / cs_ws[j];
}

// =====================================================================
extern "C" void kernel_launch(void* const* d_in, const int* in_sizes, int n_in,
                              void* d_out, int out_size, void* d_ws, size_t ws_size,
                              hipStream_t stream) {
    const float* x      = (const float*)d_in[0];
    const float* w      = (const float*)d_in[1];
    const float* ema_cs = (const float*)d_in[2];
    const float* ema_w  = (const float*)d_in[3];
    float* out = (float*)d_out;
    float* ws  = (float*)d_ws;

    float* wT     = ws + W_WT;
    float* wsq    = ws + W_SW2;
    int*   idxi   = (int*)(ws + W_IDX);
    float* counts = ws + W_CNT;
    float* dwb    = ws + W_DW;
    float* lossb  = ws + W_LOSS;
    float* cs_ws  = ws + W_CS;

    k_prep   <<<16,  256, 0, stream>>>(w, wT, wsq, counts);
    k_dist   <<<256, 512, 0, stream>>>(x, wT, wsq, idxi, out + O_IDX);
    k_quant  <<<512, 256, 0, stream>>>(x, w, idxi, out + O_Q, counts, dwb, lossb);
    k_final_a<<<1,  1024, 0, stream>>>(ema_cs, counts, lossb, cs_ws, out);
    k_final_b<<<256, 256, 0, stream>>>(ema_w, dwb, cs_ws, out);
}